// Round 26
// baseline (108.597 us; speedup 1.0000x reference)
//
#include <hip/hip_runtime.h>
#include <hip/hip_bf16.h>

// FactoredHmmLm forward on MI355X.
// ALGEBRA: nse[k*64+s]=nec[k]+nes[s] => tr[i,k*64+s]=T1[i,k]+T2[i,s]
//   => rlse = lse(T1)+lse(T2); leaf tiles are elementwise from T12.
//  1. mlp_k<1>/<2>: batched residual MLPs, 128x128 tile (BK=64, 32KB LDS,
//     4 warps x 64x64 quadrant); weights f32->bf16 on the fly.
//     mlp1 z==3 rider: CSR + esum/hlog init. mlp2 z==0: fused start-head dot.
//  2. te_k: t12 GEMM (128 blocks) + emission GEMM (tpw cvt on the fly) + hlse rider
//  3. leafc2_k: 4 elementwise leaves in swizzled LDS + combine (32KB LDS)
//  4. comb4_k x2 (64->16->4) + tail2_k (4->1 + final; hlse precomputed)

using u16 = unsigned short;
typedef __attribute__((ext_vector_type(8))) short bh8;     // 8 bf16 (4 VGPRs)
typedef __attribute__((ext_vector_type(4))) float f32x4;
typedef __attribute__((ext_vector_type(8))) unsigned short u16x8;

#define HD 256
#define TT 256
#define NB 16
#define KCL 128
#define CS 8192
#define VV 10000
#define MAXB 320
#define LOG2E 1.44269504f

__device__ __forceinline__ u16 f2bf(float v) {
  union { float f; unsigned int i; } u; u.f = v;
  unsigned int r = u.i + 0x7fffu + ((u.i >> 16) & 1u);   // RNE
  return (u16)(r >> 16);
}
__device__ __forceinline__ float bf2f(u16 u) {
  union { unsigned int i; float f; } x; x.i = ((unsigned int)u) << 16; return x.f;
}
__device__ __forceinline__ void gl2lds16(const u16* g, u16* l) {
  __builtin_amdgcn_global_load_lds(
      (const __attribute__((address_space(1))) unsigned int*)g,
      (__attribute__((address_space(3))) unsigned int*)l, 16, 0, 0);
}
__device__ __forceinline__ u16x8 cvt8(const float* __restrict__ s) {
  const float4 a = *reinterpret_cast<const float4*>(s);
  const float4 b = *reinterpret_cast<const float4*>(s + 4);
  u16x8 o;
  o[0] = f2bf(a.x); o[1] = f2bf(a.y); o[2] = f2bf(a.z); o[3] = f2bf(a.w);
  o[4] = f2bf(b.x); o[5] = f2bf(b.y); o[6] = f2bf(b.z); o[7] = f2bf(b.w);
  return o;
}
__device__ __forceinline__ u16x8 add_cvt8(const float* __restrict__ s0,
                                          const float* __restrict__ s1) {
  const float4 a0 = *reinterpret_cast<const float4*>(s0);
  const float4 b0 = *reinterpret_cast<const float4*>(s0 + 4);
  const float4 a1 = *reinterpret_cast<const float4*>(s1);
  const float4 b1 = *reinterpret_cast<const float4*>(s1 + 4);
  u16x8 o;
  o[0] = f2bf(a0.x + a1.x); o[1] = f2bf(a0.y + a1.y);
  o[2] = f2bf(a0.z + a1.z); o[3] = f2bf(a0.w + a1.w);
  o[4] = f2bf(b0.x + b1.x); o[5] = f2bf(b0.y + b1.y);
  o[6] = f2bf(b0.z + b1.z); o[7] = f2bf(b0.w + b1.w);
  return o;
}

// ---------------- batched residual-MLP GEMMs (128x128 tile) ----------------
// grid (2, 64, z). LDS: A 16KB @0 | B 16KB @16384. 4 warps, each a 64x64 quadrant.

template<int LAYER>
__global__ __launch_bounds__(256) void mlp_k(
    const float* __restrict__ ec0, const float* __restrict__ es0,
    const float* __restrict__ ec1, const float* __restrict__ es1,
    const float* __restrict__ ec2, const float* __restrict__ es2,
    u16* __restrict__ H0, u16* __restrict__ H1, u16* __restrict__ H2,
    const float* __restrict__ Wf0, const float* __restrict__ Wf1,
    const float* __restrict__ Wf2,
    const float* __restrict__ bb0, const float* __restrict__ bb1, const float* __restrict__ bb2,
    const float* __restrict__ sow, float* __restrict__ hlog,
    u16* __restrict__ Xbf, u16* __restrict__ PHb,
    const int* __restrict__ w2c, int* __restrict__ offs,
    int* __restrict__ wlist, int* __restrict__ bmap,
    float* __restrict__ esum, const float* __restrict__ sob) {
  __shared__ char lds[32768];
  const int tid = threadIdx.x, lane = tid & 63, wid = tid >> 6;
  const int z = blockIdx.z;

  if (LAYER == 1 && z == 3) {                 // CSR + init rider block
    if (blockIdx.x != 0 || blockIdx.y != 0) return;
    __shared__ int cnt[KCL], cur[KCL];
    __shared__ int wsA[2], wsB[2];
    __shared__ int totb_s;
    const int w = tid >> 6;
    if (tid < KCL) cnt[tid] = 0;
    __syncthreads();
    for (int v = tid; v < VV; v += 256) atomicAdd(&cnt[w2c[v]], 1);
    __syncthreads();
    int c = 0, x = 0;
    if (tid < KCL) {
      c = cnt[tid];
      x = c;
#pragma unroll
      for (int off = 1; off < 64; off <<= 1) {
        const int y = __shfl_up(x, off, 64);
        if (lane >= off) x += y;
      }
      if (lane == 63) wsA[w] = x;
    }
    __syncthreads();
    int nb = 0, xs = 0;
    if (tid < KCL) {
      const int base = (w == 1) ? wsA[0] : 0;
      const int excl = base + x - c;
      offs[tid] = excl;
      cur[tid] = excl;
      if (tid == KCL - 1) offs[KCL] = base + x;
      nb = (c + 63) >> 6;
      xs = nb;
#pragma unroll
      for (int off = 1; off < 64; off <<= 1) {
        const int y = __shfl_up(xs, off, 64);
        if (lane >= off) xs += y;
      }
      if (lane == 63) wsB[w] = xs;
    }
    __syncthreads();
    if (tid < KCL) {
      const int base = (w == 1) ? wsB[0] : 0;
      const int b0 = base + xs - nb;
      for (int bb = 0; bb < nb; ++bb) bmap[b0 + bb] = (tid << 8) | bb;
      if (tid == KCL - 1) totb_s = base + xs;
    }
    __syncthreads();
    const int totb = totb_s;
    for (int i = totb + tid; i < MAXB; i += 256) bmap[i] = -1;
    for (int v = tid; v < VV; v += 256) {
      const int pos = atomicAdd(&cur[w2c[v]], 1);
      wlist[pos] = v;
    }
    const float sb0 = sob[0];
    for (int i = tid; i < CS; i += 256) { esum[i] = 0.f; hlog[i] = sb0; }
    return;
  }

  const float* ec = z == 0 ? ec0 : z == 1 ? ec1 : ec2;
  const float* es = z == 0 ? es0 : z == 1 ? es1 : es2;
  u16* Hb = z == 0 ? H0 : z == 1 ? H1 : H2;
  const float* Wf = z == 0 ? Wf0 : z == 1 ? Wf1 : Wf2;
  const float* bias = z == 0 ? bb0 : z == 1 ? bb1 : bb2;

  const int rm = blockIdx.y * 128, cn = blockIdx.x * 128;
  const float* Bgf = Wf + (size_t)cn * HD;

  const int wr = wid >> 1, wc = wid & 1;      // warp -> 64x64 quadrant
  const int c0 = lane & 15, g = lane >> 4;
  const int ko = g * 8;

  f32x4 acc[4][4];
#pragma unroll
  for (int mi = 0; mi < 4; ++mi)
#pragma unroll
    for (int nj = 0; nj < 4; ++nj) acc[mi][nj] = (f32x4){0.f, 0.f, 0.f, 0.f};

  for (int kc = 0; kc < HD; kc += 64) {
    if (kc) __syncthreads();
#pragma unroll
    for (int i = 0; i < 4; ++i) {
      const int c = i * 256 + tid;            // 0..1023: 128 rows x 8 chunks
      const int r = c >> 3, cb = c & 7;
      if (LAYER == 1) {
        const int grow = rm + r;
        const u16x8 v = add_cvt8(ec + (grow >> 6) * HD + kc + cb * 8,
                                 es + (grow & 63) * HD + kc + cb * 8);
        *reinterpret_cast<u16x8*>(&lds[r * 128 + ((cb * 16) ^ ((r & 7) << 4))]) = v;
      } else {
        const int gq = cb ^ (r & 7);
        gl2lds16(Hb + (size_t)(rm + r) * HD + kc + gq * 8, (u16*)&lds[c * 16]);
      }
      const u16x8 bv = cvt8(Bgf + (size_t)r * HD + kc + cb * 8);
      *reinterpret_cast<u16x8*>(&lds[16384 + r * 128 + ((cb * 16) ^ ((r & 7) << 4))]) = bv;
    }
    __syncthreads();
#pragma unroll
    for (int kk = 0; kk < 64; kk += 32) {
      const int kb = (kk + ko) * 2;
      bh8 af[4], bf[4];
#pragma unroll
      for (int mi = 0; mi < 4; ++mi) {
        const int ar = wr * 64 + mi * 16 + c0;
        af[mi] = *reinterpret_cast<const bh8*>(&lds[ar * 128 + (kb ^ ((ar & 7) << 4))]);
      }
#pragma unroll
      for (int nj = 0; nj < 4; ++nj) {
        const int br = wc * 64 + nj * 16 + c0;
        bf[nj] = *reinterpret_cast<const bh8*>(&lds[16384 + br * 128 + (kb ^ ((br & 7) << 4))]);
      }
#pragma unroll
      for (int mi = 0; mi < 4; ++mi)
#pragma unroll
        for (int nj = 0; nj < 4; ++nj)
          acc[mi][nj] = __builtin_amdgcn_mfma_f32_16x16x32_bf16(af[mi], bf[nj], acc[mi][nj], 0, 0, 0);
    }
  }

  float pd[4][4];                              // head-dot partials [mi][reg]
#pragma unroll
  for (int mi = 0; mi < 4; ++mi)
#pragma unroll
    for (int reg = 0; reg < 4; ++reg) pd[mi][reg] = 0.f;

#pragma unroll
  for (int nj = 0; nj < 4; ++nj) {
    const int nidx = cn + wc * 64 + nj * 16 + c0;
    const float bv = bias[nidx];
#pragma unroll
    for (int mi = 0; mi < 4; ++mi) {
#pragma unroll
      for (int reg = 0; reg < 4; ++reg) {
        const int midx = rm + wr * 64 + mi * 16 + g * 4 + reg;
        float v = acc[mi][nj][reg] + bv;
        if (LAYER == 2)
          v += ec[(midx >> 6) * HD + nidx] + es[(midx & 63) * HD + nidx];
        v = fmaxf(v, 0.f);
        if (LAYER == 1) {
          Hb[(size_t)midx * 256 + nidx] = f2bf(v);
        } else {
          if (z == 0) pd[mi][reg] += v * sow[nidx];
          else if (z == 1) Xbf[(size_t)midx * 256 + nidx] = f2bf(v);
          else PHb[(size_t)midx * 256 + nidx] = f2bf(v);
        }
      }
    }
  }
  if (LAYER == 2 && blockIdx.z == 0) {
#pragma unroll
    for (int off = 1; off < 16; off <<= 1)
#pragma unroll
      for (int mi = 0; mi < 4; ++mi)
#pragma unroll
        for (int reg = 0; reg < 4; ++reg)
          pd[mi][reg] += __shfl_xor(pd[mi][reg], off, 64);
    if (c0 == 0) {
#pragma unroll
      for (int mi = 0; mi < 4; ++mi)
#pragma unroll
        for (int reg = 0; reg < 4; ++reg)
          atomicAdd(&hlog[rm + wr * 64 + mi * 16 + g * 4 + reg], pd[mi][reg]);
    }
  }
}

// ---------------- te_k: t12 GEMM + emission GEMM + hlse rider --------

__global__ __launch_bounds__(256) void te_k(
    const u16* __restrict__ Xbf, const float* __restrict__ nec,
    const float* __restrict__ nes,
    float* __restrict__ T12, float* __restrict__ rlse,
    const float* __restrict__ tpw, const u16* __restrict__ PHb,
    const float* __restrict__ bp,
    const int* __restrict__ offs, const int* __restrict__ wlist,
    const int* __restrict__ map,
    float* __restrict__ esum, float* __restrict__ logits_all,
    const float* __restrict__ hlog, float* __restrict__ hlseb) {
  __shared__ char lds[32768];
  const int tid = threadIdx.x, lane = tid & 63, wid = tid >> 6;
  const int rb0 = lane & 15;
  const int ko = (lane >> 4) * 8;
  const int g = lane >> 4, c0 = lane & 15;

  if (blockIdx.x == CS / 64 + MAXB) {
    // ---------- hlse rider: logsumexp over hlog[0..CS) ----------
    __shared__ float redm[4];
    float mm = -1e30f;
    for (int i = tid; i < CS; i += 256) mm = fmaxf(mm, hlog[i]);
    for (int off = 32; off; off >>= 1) mm = fmaxf(mm, __shfl_xor(mm, off, 64));
    if (lane == 0) redm[wid] = mm;
    __syncthreads();
    const float M = fmaxf(fmaxf(redm[0], redm[1]), fmaxf(redm[2], redm[3]));
    float sx = 0.f;
    for (int i = tid; i < CS; i += 256) sx += expf(hlog[i] - M);
    for (int off = 32; off; off >>= 1) sx += __shfl_xor(sx, off, 64);
    __syncthreads();
    if (lane == 0) redm[wid] = sx;
    __syncthreads();
    if (tid == 0) hlseb[0] = M + logf(redm[0] + redm[1] + redm[2] + redm[3]);
    return;
  }

  if (blockIdx.x < CS / 64) {
    // ---------- t12 part ----------
    const int rm = blockIdx.x * 64;
    const int ra = wid * 16 + (lane & 15);
    f32x4 acc[12];
#pragma unroll
    for (int i = 0; i < 12; ++i) acc[i] = (f32x4){0.f, 0.f, 0.f, 0.f};

    for (int kc = 0; kc < HD; kc += 64) {
      if (kc) __syncthreads();
#pragma unroll
      for (int i = 0; i < 2; ++i) {
        const int c = i * 256 + tid;
        const int r = c >> 3, cb = c & 7;
        const int gq = cb ^ (r & 7);
        gl2lds16(Xbf + (size_t)(rm + r) * HD + kc + gq * 8, (u16*)&lds[c * 16]);
      }
#pragma unroll
      for (int i = 0; i < 6; ++i) {
        const int c = i * 256 + tid;        // 0..1535 -> 192 rows x 8 chunks
        const int r = c >> 3, cb = c & 7;
        const float* src = (r < KCL) ? (nec + r * HD + kc + cb * 8)
                                     : (nes + (r - KCL) * HD + kc + cb * 8);
        const u16x8 v = cvt8(src);
        *reinterpret_cast<u16x8*>(&lds[8192 + r * 128 + ((cb * 16) ^ ((r & 7) << 4))]) = v;
      }
      __syncthreads();
#pragma unroll
      for (int kk = 0; kk < 64; kk += 32) {
        const int kb = (kk + ko) * 2;
        const bh8 af = *reinterpret_cast<const bh8*>(&lds[ra * 128 + (kb ^ ((ra & 7) << 4))]);
#pragma unroll
        for (int nj = 0; nj < 12; ++nj) {
          const int rb = nj * 16 + rb0;
          const bh8 bf = *reinterpret_cast<const bh8*>(&lds[8192 + rb * 128 + (kb ^ ((rb & 7) << 4))]);
          acc[nj] = __builtin_amdgcn_mfma_f32_16x16x32_bf16(af, bf, acc[nj], 0, 0, 0);
        }
      }
    }

    float rs1[4] = {0.f, 0.f, 0.f, 0.f};
    float rs2[4] = {0.f, 0.f, 0.f, 0.f};
#pragma unroll
    for (int nj = 0; nj < 12; ++nj) {
      const int col = nj * 16 + c0;
#pragma unroll
      for (int reg = 0; reg < 4; ++reg) {
        const int row = rm + wid * 16 + g * 4 + reg;
        const float v = acc[nj][reg];
        T12[(size_t)row * 192 + col] = v;
        const float e = exp2f(v * LOG2E);
        if (nj < 8) rs1[reg] += e; else rs2[reg] += e;
      }
    }
#pragma unroll
    for (int off = 1; off < 16; off <<= 1)
#pragma unroll
      for (int reg = 0; reg < 4; ++reg) {
        rs1[reg] += __shfl_xor(rs1[reg], off, 64);
        rs2[reg] += __shfl_xor(rs2[reg], off, 64);
      }
    if (c0 == 0) {
#pragma unroll
      for (int reg = 0; reg < 4; ++reg)
        rlse[rm + wid * 16 + g * 4 + reg] = logf(rs1[reg]) + logf(rs2[reg]);
    }
    return;
  }

  // ---------- emission part ----------
  const int ent = map[blockIdx.x - CS / 64];
  if (ent < 0) return;
  const int c = ent >> 8, blk = ent & 255;
  __shared__ int wid_s[64];
  const int st = offs[c], cnt = offs[c + 1] - st;
  if (tid < 64) {
    const int idx = blk * 64 + tid;
    wid_s[tid] = (idx < cnt) ? wlist[st + idx] : -1;
  }
  __syncthreads();

  f32x4 acc[4];
#pragma unroll
  for (int i = 0; i < 4; ++i) acc[i] = (f32x4){0.f, 0.f, 0.f, 0.f};
  const int ra = wid * 16 + (lane & 15);
  const u16* Bg = PHb + (size_t)(c * 64) * HD;

  for (int kc = 0; kc < HD; kc += 64) {
    if (kc) __syncthreads();
#pragma unroll
    for (int i = 0; i < 2; ++i) {
      const int cc = i * 256 + tid;
      const int r = cc >> 3, cb = cc & 7;
      const int gq = cb ^ (r & 7);
      const int wv = max(wid_s[r], 0);
      const u16x8 av = cvt8(tpw + (size_t)wv * HD + kc + cb * 8);
      *reinterpret_cast<u16x8*>(&lds[r * 128 + ((cb * 16) ^ ((r & 7) << 4))]) = av;
      gl2lds16(Bg + (size_t)r * HD + kc + gq * 8, (u16*)&lds[8192 + cc * 16]);
    }
    __syncthreads();
#pragma unroll
    for (int kk = 0; kk < 64; kk += 32) {
      const int kb = (kk + ko) * 2;
      const bh8 af = *reinterpret_cast<const bh8*>(&lds[ra * 128 + (kb ^ ((ra & 7) << 4))]);
#pragma unroll
      for (int nj = 0; nj < 4; ++nj) {
        const int rb = nj * 16 + rb0;
        const bh8 bf = *reinterpret_cast<const bh8*>(&lds[8192 + rb * 128 + (kb ^ ((rb & 7) << 4))]);
        acc[nj] = __builtin_amdgcn_mfma_f32_16x16x32_bf16(af, bf, acc[nj], 0, 0, 0);
      }
    }
  }

#pragma unroll
  for (int nj = 0; nj < 4; ++nj) {
    float se = 0.f;
#pragma unroll
    for (int reg = 0; reg < 4; ++reg) {
      const int row = wid * 16 + g * 4 + reg;
      const int w = wid_s[row];
      if (w >= 0) {
        const float lg = acc[nj][reg] + bp[w];
        logits_all[(size_t)w * 64 + nj * 16 + c0] = lg;
        se += expf(lg);
      }
    }
    se += __shfl_xor(se, 16, 64);
    se += __shfl_xor(se, 32, 64);
    if (g == 0) atomicAdd(&esum[c * 64 + nj * 16 + c0], se);
  }
}

// ---------------- quad combine core (32KB LDS: P/ftile reuse dead slots) --------

__device__ __forceinline__ void comb4_core(
    char* lds, float* wpm,
    float sc0, float sc1, float sc2, float sc3,
    u16* node, float* dsc, int parity, int tid) {
  const int lane = tid & 63, w = tid >> 6;
  const int p = w >> 1, h = w & 1;
  const int abase = p * 16384, bbase = abase + 8192;
  const int c0 = lane & 15, g = lane >> 4;
  f32x4 a2[2][4];
#pragma unroll
  for (int mi = 0; mi < 2; ++mi)
#pragma unroll
    for (int nj = 0; nj < 4; ++nj) a2[mi][nj] = (f32x4){0.f, 0.f, 0.f, 0.f};
#pragma unroll
  for (int kk = 0; kk < 64; kk += 32) {
    const int kb = (kk + g * 8) * 2;
    bh8 af[2], bf[4];
#pragma unroll
    for (int mi = 0; mi < 2; ++mi) {
      const int ar = h * 32 + mi * 16 + c0;
      af[mi] = *reinterpret_cast<const bh8*>(&lds[abase + ar * 128 + (kb ^ ((ar & 7) << 4))]);
    }
#pragma unroll
    for (int nj = 0; nj < 4; ++nj) {
      const int br = nj * 16 + c0;
      bf[nj] = *reinterpret_cast<const bh8*>(&lds[bbase + br * 128 + (kb ^ ((br & 7) << 4))]);
    }
#pragma unroll
    for (int mi = 0; mi < 2; ++mi)
#pragma unroll
      for (int nj = 0; nj < 4; ++nj)
        a2[mi][nj] = __builtin_amdgcn_mfma_f32_16x16x32_bf16(af[mi], bf[nj], a2[mi][nj], 0, 0, 0);
  }
  float mx = 0.f;
#pragma unroll
  for (int mi = 0; mi < 2; ++mi)
#pragma unroll
    for (int nj = 0; nj < 4; ++nj)
#pragma unroll
      for (int reg = 0; reg < 4; ++reg) mx = fmaxf(mx, a2[mi][nj][reg]);
#pragma unroll
  for (int off = 1; off < 64; off <<= 1) mx = fmaxf(mx, __shfl_xor(mx, off, 64));
  if (lane == 0) wpm[w] = mx;
  __syncthreads();                 // all stage-1 MFMAs done -> slots 0..3 dead
  const float mp = fmaxf(wpm[p * 2], wpm[p * 2 + 1]);
  const float invp = 1.0f / mp;
#pragma unroll
  for (int mi = 0; mi < 2; ++mi)
#pragma unroll
    for (int nj = 0; nj < 4; ++nj)
#pragma unroll
      for (int reg = 0; reg < 4; ++reg) {
        const int row = h * 32 + mi * 16 + g * 4 + reg;
        const int col = nj * 16 + c0;
        const u16 val = f2bf(a2[mi][nj][reg] * invp);
        if (p == 0)                // P1 -> slot0 region (@0)
          *reinterpret_cast<u16*>(&lds[row * 128 + ((col * 2) ^ ((row & 7) << 4))]) = val;
        else                       // P2 -> slot1 region (@8192), transposed
          *reinterpret_cast<u16*>(&lds[8192 + col * 128 + ((row * 2) ^ ((col & 7) << 4))]) = val;
      }
  __syncthreads();

  f32x4 acc[4];
#pragma unroll
  for (int i = 0; i < 4; ++i) acc[i] = (f32x4){0.f, 0.f, 0.f, 0.f};
  const int ra = w * 16 + c0;
#pragma unroll
  for (int kk = 0; kk < 64; kk += 32) {
    const int kb = (kk + g * 8) * 2;
    const bh8 af = *reinterpret_cast<const bh8*>(&lds[ra * 128 + (kb ^ ((ra & 7) << 4))]);
#pragma unroll
    for (int nj = 0; nj < 4; ++nj) {
      const int rb = nj * 16 + c0;
      const bh8 bf = *reinterpret_cast<const bh8*>(&lds[8192 + rb * 128 + (kb ^ ((rb & 7) << 4))]);
      acc[nj] = __builtin_amdgcn_mfma_f32_16x16x32_bf16(af, bf, acc[nj], 0, 0, 0);
    }
  }
  float mx2 = 0.f;
#pragma unroll
  for (int nj = 0; nj < 4; ++nj)
#pragma unroll
    for (int reg = 0; reg < 4; ++reg) mx2 = fmaxf(mx2, acc[nj][reg]);
#pragma unroll
  for (int off = 1; off < 64; off <<= 1) mx2 = fmaxf(mx2, __shfl_xor(mx2, off, 64));
  if (lane == 0) wpm[4 + w] = mx2;
  __syncthreads();                 // all stage-2 MFMAs done -> P1/P2 dead
  const float m = fmaxf(fmaxf(wpm[4], wpm[5]), fmaxf(wpm[6], wpm[7]));
  const float inv = 1.0f / m;
  float* ftile = reinterpret_cast<float*>(lds + 16384);   // reuses slots 2-3
#pragma unroll
  for (int nj = 0; nj < 4; ++nj)
#pragma unroll
    for (int reg = 0; reg < 4; ++reg)
      ftile[(w * 16 + g * 4 + reg) * 64 + nj * 16 + c0] = acc[nj][reg] * inv;
  __syncthreads();
  const int rr = tid >> 2, cb = (tid & 3) * 16;
  u16x8 o0, o1;
  if (parity == 0) {
#pragma unroll
    for (int e = 0; e < 8; ++e) o0[e] = f2bf(ftile[rr * 64 + cb + e]);
#pragma unroll
    for (int e = 0; e < 8; ++e) o1[e] = f2bf(ftile[rr * 64 + cb + 8 + e]);
  } else {
#pragma unroll
    for (int e = 0; e < 8; ++e) o0[e] = f2bf(ftile[(cb + e) * 64 + rr]);
#pragma unroll
    for (int e = 0; e < 8; ++e) o1[e] = f2bf(ftile[(cb + 8 + e) * 64 + rr]);
  }
  *reinterpret_cast<u16x8*>(node + rr * 64 + cb) = o0;
  *reinterpret_cast<u16x8*>(node + rr * 64 + cb + 8) = o1;
  if (tid == 0)
    *dsc = sc0 + sc1 + sc2 + sc3
         + logf(fmaxf(wpm[0], wpm[1])) + logf(fmaxf(wpm[2], wpm[3])) + logf(m);
}

__device__ __forceinline__ void comb4_stage(
    char* lds, const u16* s0, const u16* s1, const u16* s2, const u16* s3, int tid) {
  const u16* srcs[4] = {s0, s1, s2, s3};
  const int sr = tid >> 3, scb = (tid & 7) * 16;
#pragma unroll
  for (int nd = 0; nd < 4; ++nd)
#pragma unroll
    for (int rep = 0; rep < 2; ++rep) {
      const int r = rep * 32 + sr;
      const bh8 v = *reinterpret_cast<const bh8*>(srcs[nd] + r * 64 + (scb >> 1));
      *reinterpret_cast<bh8*>(&lds[nd * 8192 + r * 128 + (scb ^ ((r & 7) << 4))]) = v;
    }
  __syncthreads();
}

// ---------------- leafc2_k: 4 elementwise leaves in LDS + combine ----------------

__global__ __launch_bounds__(256) void leafc2_k(
    const float* __restrict__ T12, const float* __restrict__ rlse,
    const float* __restrict__ lall, const float* __restrict__ esum,
    const int* __restrict__ text, const int* __restrict__ w2c,
    u16* __restrict__ dst, float* __restrict__ scd) {
  __shared__ char lds[32768];
  __shared__ float wpm[8];
  __shared__ float scl[4];
  __shared__ float ev_s[64];
  const int tid = threadIdx.x, lane = tid & 63, w = tid >> 6;
  const int n = blockIdx.x >> 6, u = blockIdx.x & 63;
  const int r = tid >> 2, cb = (tid & 3) * 16;

  for (int j = 0; j < 4; ++j) {
    const int l = 4 * u + j;
    char* slot = &lds[j * 8192];
    __syncthreads();
    if (l == 255) {
      for (int idx = tid; idx < 4096; idx += 256) {
        const int rr = idx >> 6, cc = idx & 63;
        const u16 val = (rr == cc) ? (u16)0x3F80 : (u16)0;
        *reinterpret_cast<u16*>(&slot[cc * 128 + ((rr * 2) ^ ((cc & 7) << 4))]) = val;
      }
      if (tid == 0) scl[j] = 0.f;
      continue;
    }
    const int ttv = l + 1;
    const int wcur = text[n * TT + ttv];
    const int cp = w2c[text[n * TT + ttv - 1]];
    const int cc = w2c[wcur];
    if (tid < 64)
      ev_s[tid] = lall[(size_t)wcur * 64 + tid] - logf(esum[cc * 64 + tid]);
    __syncthreads();
    const int grow = cp * 64 + r;
    const float base = T12[(size_t)grow * 192 + cc] - rlse[grow];
    const float* t2row = T12 + (size_t)grow * 192 + 128 + cb;
    float L[16];
    float mx = -1e30f;
#pragma unroll
    for (int e = 0; e < 16; ++e) {
      L[e] = base + t2row[e] + ev_s[cb + e];
      mx = fmaxf(mx, L[e]);
    }
#pragma unroll
    for (int off = 1; off < 64; off <<= 1) mx = fmaxf(mx, __shfl_xor(mx, off, 64));
    if (lane == 0) wpm[w] = mx;
    __syncthreads();
    const float m = fmaxf(fmaxf(wpm[0], wpm[1]), fmaxf(wpm[2], wpm[3]));
    if ((j & 1) == 0) {
      u16x8 o0, o1;
#pragma unroll
      for (int e = 0; e < 8; ++e) o0[e] = f2bf(exp2f((L[e] - m) * LOG2E));
#pragma unroll
      for (int e = 0; e < 8; ++e) o1[e] = f2bf(exp2f((L[8 + e] - m) * LOG2E));
      const int sw = (r & 7) << 4;
      *reinterpret_cast<u16x8*>(&slot[r * 128 + ((cb * 2) ^ sw)]) = o0;
      *reinterpret_cast<u16x8*>(&slot[r * 128 + ((cb * 2 + 16) ^ sw)]) = o1;
    } else {
#pragma unroll
      for (int e = 0; e < 16; ++e) {
        const int col = cb + e;
        const u16 val = f2bf(exp2f((L[e] - m) * LOG2E));
        *reinterpret_cast<u16*>(&slot[col * 128 + ((r * 2) ^ ((col & 7) << 4))]) = val;
      }
    }
    if (tid == 0) scl[j] = m;
  }
  __syncthreads();
  comb4_core(lds, wpm, scl[0], scl[1], scl[2], scl[3],
             dst + ((size_t)(n * 64 + u)) * 4096, &scd[n * 64 + u], u & 1, tid);
}

__global__ __launch_bounds__(256) void comb4_k(const u16* __restrict__ src,
                                               const float* __restrict__ scs,
                                               u16* __restrict__ dst,
                                               float* __restrict__ scd, int U) {
  const int n = blockIdx.x / U, u = blockIdx.x % U;
  __shared__ char lds[32768];
  __shared__ float wpm[8];
  const u16* base = src + ((size_t)(n * 4 * U + 4 * u)) * 4096;
  const float* sb = scs + n * 4 * U + 4 * u;
  comb4_stage(lds, base, base + 4096, base + 2 * 4096, base + 3 * 4096, threadIdx.x);
  comb4_core(lds, wpm, sb[0], sb[1], sb[2], sb[3],
             dst + ((size_t)(n * U + u)) * 4096, &scd[n * U + u], u & 1, threadIdx.x);
}

// ---------------- tail2: 4 -> 1 + final (hlse precomputed by te_k rider) --------

__global__ __launch_bounds__(256) void tail2_k(
    const u16* __restrict__ nodes, const float* __restrict__ nsc,
    u16* __restrict__ rootb,
    const float* __restrict__ hlog, const float* __restrict__ hlseb,
    const float* __restrict__ lall,
    const float* __restrict__ esum, const int* __restrict__ text,
    const int* __restrict__ w2c, float* __restrict__ out) {
  __shared__ char lds[32768];
  __shared__ float wpm[8];
  __shared__ float rsc_s;
  const int n = blockIdx.x, tid = threadIdx.x;

  const u16* src = nodes + (size_t)n * 4 * 4096;
  const float* sc = nsc + n * 4;
  u16* root = rootb + (size_t)n * 4096;
  comb4_stage(lds, src, src + 4096, src + 2 * 4096, src + 3 * 4096, tid);
  comb4_core(lds, wpm, sc[0], sc[1], sc[2], sc[3], root, &rsc_s, 0, tid);
  __syncthreads();

  if (tid < 64) {
    const int i = tid;
    const float hlse = hlseb[0];
    const int w0 = text[n * TT];
    const int cc = w2c[w0];
    const float ev = lall[(size_t)w0 * 64 + i] - logf(esum[cc * 64 + i]);
    float a0 = hlog[cc * 64 + i] - hlse + ev;
    float m0 = a0;
    for (int off = 32; off; off >>= 1) m0 = fmaxf(m0, __shfl_xor(m0, off, 64));
    const float lin = expf(a0 - m0);
    const u16* row = root + i * 64;
    float rs = 0.f;
#pragma unroll
    for (int e8 = 0; e8 < 8; ++e8) {
      const u16x8 v = *reinterpret_cast<const u16x8*>(row + e8 * 8);
#pragma unroll
      for (int e = 0; e < 8; ++e) rs += bf2f(v[e]);
    }
    float v = lin * rs;
    for (int off = 32; off; off >>= 1) v += __shfl_xor(v, off, 64);
    if (i == 0) out[n] = m0 + rsc_s + logf(v);
  }
}

// ---------------- host orchestration ----------------

extern "C" void kernel_launch(void* const* d_in, const int* in_sizes, int n_in,
                              void* d_out, int out_size, void* d_ws, size_t ws_size,
                              hipStream_t stream) {
  (void)in_sizes; (void)n_in; (void)out_size; (void)ws_size;
  const int* text = (const int*)d_in[0];
  const int* w2c  = (const int*)d_in[1];
  const float* sec = (const float*)d_in[2];
  const float* ses = (const float*)d_in[3];
  const float* stc = (const float*)d_in[4];
  const float* sts = (const float*)d_in[5];
  const float* nec = (const float*)d_in[6];
  const float* nes = (const float*)d_in[7];
  const float* pec = (const float*)d_in[8];
  const float* pes = (const float*)d_in[9];
  const float* srw1 = (const float*)d_in[10];
  const float* srb1 = (const float*)d_in[11];
  const float* srw2 = (const float*)d_in[12];
  const float* srb2 = (const float*)d_in[13];
  const float* trw1 = (const float*)d_in[14];
  const float* trb1 = (const float*)d_in[15];
  const float* trw2 = (const float*)d_in[16];
  const float* trb2 = (const float*)d_in[17];
  const float* tew1 = (const float*)d_in[18];
  const float* teb1 = (const float*)d_in[19];
  const float* tew2 = (const float*)d_in[20];
  const float* teb2 = (const float*)d_in[21];
  const float* sow = (const float*)d_in[22];
  const float* sob = (const float*)d_in[23];
  const float* tpw = (const float*)d_in[24];
  const float* tpb = (const float*)d_in[25];
  float* out = (float*)d_out;

  char* p = (char*)d_ws;
  auto carve = [&](size_t bytes) -> char* {
    char* r = p; p += (bytes + 255) & ~(size_t)255; return r;
  };
  u16* Hb0  = (u16*)carve((size_t)CS * HD * 2);
  u16* Hb1  = (u16*)carve((size_t)CS * HD * 2);
  u16* Hb2  = (u16*)carve((size_t)CS * HD * 2);
  u16* Xbf  = (u16*)carve((size_t)CS * HD * 2);
  u16* PHb  = (u16*)carve((size_t)CS * HD * 2);
  float* T12  = (float*)carve((size_t)CS * 192 * 4);
  float* hlog  = (float*)carve(CS * 4);
  float* rlse  = (float*)carve(CS * 4);
  float* hlseb = (float*)carve(256);
  int* offs    = (int*)carve((KCL + 1) * 4);
  int* wlist   = (int*)carve(VV * 4);
  int* bmap    = (int*)carve(MAXB * 4);
  float* esum  = (float*)carve(CS * 4);
  float* lall  = (float*)carve((size_t)VV * 64 * 4);
  u16*   bufA  = (u16*)carve((size_t)NB * 64 * 4096 * 2);   // L1 out
  u16*   bufB  = (u16*)carve((size_t)NB * 16 * 4096 * 2);   // L2 out
  u16*   bufC  = (u16*)carve((size_t)NB * 4 * 4096 * 2);    // L3 out
  u16*   rootb = (u16*)carve((size_t)NB * 4096 * 2);
  float* scA   = (float*)carve((size_t)NB * 64 * 4);
  float* scB   = (float*)carve((size_t)NB * 16 * 4);
  float* scC   = (float*)carve((size_t)NB * 4 * 4);

  // layer 1, 128x128 tile (+ CSR/init rider at z==3)
  mlp_k<1><<<dim3(2, 64, 4), 256, 0, stream>>>(
      sec, ses, stc, sts, pec, pes, Hb0, Hb1, Hb2,
      srw1, trw1, tew1, srb1, trb1, teb1,
      sow, hlog, nullptr, nullptr,
      w2c, offs, wlist, bmap, esum, sob);
  // layer 2, 128x128 tile (head dot fused at z==0)
  mlp_k<2><<<dim3(2, 64, 3), 256, 0, stream>>>(
      sec, ses, stc, sts, pec, pes, Hb0, Hb1, Hb2,
      srw2, trw2, tew2, srb2, trb2, teb2,
      sow, hlog, Xbf, PHb,
      w2c, offs, wlist, bmap, esum, sob);

  // t12 GEMM + emission + hlse rider in one launch
  te_k<<<CS / 64 + MAXB + 1, 256, 0, stream>>>(
      Xbf, nec, nes, T12, rlse, tpw, PHb, tpb, offs, wlist, bmap, esum, lall,
      hlog, hlseb);

  // fused elementwise-leaf + level-1 combine: 256 leaves -> 64 nodes per seq
  leafc2_k<<<NB * 64, 256, 0, stream>>>(
      T12, rlse, lall, esum, text, w2c, bufA, scA);

  comb4_k<<<NB * 16, 256, 0, stream>>>(bufA, scA, bufB, scB, 16);
  comb4_k<<<NB * 4, 256, 0, stream>>>(bufB, scB, bufC, scC, 4);
  tail2_k<<<NB, 256, 0, stream>>>(bufC, scC, rootb, hlog, hlseb, lall, esum,
                                  text, w2c, out);
}

// Round 27
// 95.126 us; speedup vs baseline: 1.1416x; 1.1416x over previous
//
#include <hip/hip_runtime.h>
#include <hip/hip_bf16.h>

// FactoredHmmLm forward on MI355X.
// ALGEBRA 1: nse[k*64+s]=nec[k]+nes[s] => tr[i,k*64+s]=T1[i,k]+T2[i,s]
//   => rlse = lse(T1)+lse(T2); leaf tiles are elementwise from T12.
// ALGEBRA 2 (layer-1 MLP): E[k*64+s]=ec[k]+es[s] => E@W1^T = P1[k]+P2[s]
//   => H = relu(P1[k]+P2[s]+b1) is ELEMENTWISE from P = [ec;es]@W1^T (192x256/chain)
//  1. p12_k: P = [ec;es]@W1^T + b1-fold (12 blocks) + CSR/esum/hlog rider
//  2. mlp2_k: layer-2 GEMM, 64x64 tile; A = relu(P1+P2) built in staging (no Hb);
//     z==0 fuses start-head dot via atomicAdd into hlog
//  3. te_k: t12 GEMM (128 blocks) + emission GEMM (tpw cvt on the fly) + hlse rider
//  4. leafc2_k: 4 elementwise leaves in swizzled LDS + combine (32KB LDS)
//  5. comb4_k x2 (64->16->4) + tail2_k (4->1 + final; hlse precomputed)

using u16 = unsigned short;
typedef __attribute__((ext_vector_type(8))) short bh8;     // 8 bf16 (4 VGPRs)
typedef __attribute__((ext_vector_type(4))) float f32x4;
typedef __attribute__((ext_vector_type(8))) unsigned short u16x8;

#define HD 256
#define TT 256
#define NB 16
#define KCL 128
#define CS 8192
#define VV 10000
#define MAXB 320
#define LOG2E 1.44269504f

__device__ __forceinline__ u16 f2bf(float v) {
  union { float f; unsigned int i; } u; u.f = v;
  unsigned int r = u.i + 0x7fffu + ((u.i >> 16) & 1u);   // RNE
  return (u16)(r >> 16);
}
__device__ __forceinline__ float bf2f(u16 u) {
  union { unsigned int i; float f; } x; x.i = ((unsigned int)u) << 16; return x.f;
}
__device__ __forceinline__ void gl2lds16(const u16* g, u16* l) {
  __builtin_amdgcn_global_load_lds(
      (const __attribute__((address_space(1))) unsigned int*)g,
      (__attribute__((address_space(3))) unsigned int*)l, 16, 0, 0);
}
__device__ __forceinline__ u16x8 cvt8(const float* __restrict__ s) {
  const float4 a = *reinterpret_cast<const float4*>(s);
  const float4 b = *reinterpret_cast<const float4*>(s + 4);
  u16x8 o;
  o[0] = f2bf(a.x); o[1] = f2bf(a.y); o[2] = f2bf(a.z); o[3] = f2bf(a.w);
  o[4] = f2bf(b.x); o[5] = f2bf(b.y); o[6] = f2bf(b.z); o[7] = f2bf(b.w);
  return o;
}
__device__ __forceinline__ u16x8 relu_add_cvt8(const float* __restrict__ s0,
                                               const float* __restrict__ s1) {
  const float4 a0 = *reinterpret_cast<const float4*>(s0);
  const float4 b0 = *reinterpret_cast<const float4*>(s0 + 4);
  const float4 a1 = *reinterpret_cast<const float4*>(s1);
  const float4 b1 = *reinterpret_cast<const float4*>(s1 + 4);
  u16x8 o;
  o[0] = f2bf(fmaxf(a0.x + a1.x, 0.f)); o[1] = f2bf(fmaxf(a0.y + a1.y, 0.f));
  o[2] = f2bf(fmaxf(a0.z + a1.z, 0.f)); o[3] = f2bf(fmaxf(a0.w + a1.w, 0.f));
  o[4] = f2bf(fmaxf(b0.x + b1.x, 0.f)); o[5] = f2bf(fmaxf(b0.y + b1.y, 0.f));
  o[6] = f2bf(fmaxf(b0.z + b1.z, 0.f)); o[7] = f2bf(fmaxf(b0.w + b1.w, 0.f));
  return o;
}

// ---------------- p12_k: P = [ec;es] @ W1^T (+b1 on ec rows) + CSR rider ------
// grid (4, 4): x = 64-col tile of W1-output, y = chain z (y==3,x==0: CSR rider).
// LDS: A (W1 rows) 8KB @0 | B ([ec;es] rows) 24KB @8192.

__global__ __launch_bounds__(256) void p12_k(
    const float* __restrict__ ec0, const float* __restrict__ es0,
    const float* __restrict__ ec1, const float* __restrict__ es1,
    const float* __restrict__ ec2, const float* __restrict__ es2,
    const float* __restrict__ Wf0, const float* __restrict__ Wf1,
    const float* __restrict__ Wf2,
    const float* __restrict__ b0, const float* __restrict__ b1_, const float* __restrict__ b2,
    float* __restrict__ Pb,
    const int* __restrict__ w2c, int* __restrict__ offs,
    int* __restrict__ wlist, int* __restrict__ bmap,
    float* __restrict__ esum, float* __restrict__ hlog,
    const float* __restrict__ sob) {
  const int tid = threadIdx.x, lane = tid & 63, wid = tid >> 6;
  const int z = blockIdx.y;

  if (z == 3) {                               // CSR + init rider
    if (blockIdx.x != 0) return;
    __shared__ int cnt[KCL], cur[KCL];
    __shared__ int wsA[2], wsB[2];
    __shared__ int totb_s;
    const int w = tid >> 6;
    if (tid < KCL) cnt[tid] = 0;
    __syncthreads();
    for (int v = tid; v < VV; v += 256) atomicAdd(&cnt[w2c[v]], 1);
    __syncthreads();
    int c = 0, x = 0;
    if (tid < KCL) {
      c = cnt[tid];
      x = c;
#pragma unroll
      for (int off = 1; off < 64; off <<= 1) {
        const int y = __shfl_up(x, off, 64);
        if (lane >= off) x += y;
      }
      if (lane == 63) wsA[w] = x;
    }
    __syncthreads();
    int nb = 0, xs = 0;
    if (tid < KCL) {
      const int base = (w == 1) ? wsA[0] : 0;
      const int excl = base + x - c;
      offs[tid] = excl;
      cur[tid] = excl;
      if (tid == KCL - 1) offs[KCL] = base + x;
      nb = (c + 63) >> 6;
      xs = nb;
#pragma unroll
      for (int off = 1; off < 64; off <<= 1) {
        const int y = __shfl_up(xs, off, 64);
        if (lane >= off) xs += y;
      }
      if (lane == 63) wsB[w] = xs;
    }
    __syncthreads();
    if (tid < KCL) {
      const int base = (w == 1) ? wsB[0] : 0;
      const int bq = base + xs - nb;
      for (int bb = 0; bb < nb; ++bb) bmap[bq + bb] = (tid << 8) | bb;
      if (tid == KCL - 1) totb_s = base + xs;
    }
    __syncthreads();
    const int totb = totb_s;
    for (int i = totb + tid; i < MAXB; i += 256) bmap[i] = -1;
    for (int v = tid; v < VV; v += 256) {
      const int pos = atomicAdd(&cur[w2c[v]], 1);
      wlist[pos] = v;
    }
    const float sb0 = sob[0];
    for (int i = tid; i < CS; i += 256) { esum[i] = 0.f; hlog[i] = sb0; }
    return;
  }

  __shared__ char lds[32768];
  const float* ec = z == 0 ? ec0 : z == 1 ? ec1 : ec2;
  const float* es = z == 0 ? es0 : z == 1 ? es1 : es2;
  const float* Wf = z == 0 ? Wf0 : z == 1 ? Wf1 : Wf2;
  const float* bias = z == 0 ? b0 : z == 1 ? b1_ : b2;
  float* P = Pb + (size_t)z * 192 * HD;

  const int j0 = blockIdx.x * 64;
  const int ra = wid * 16 + (lane & 15);
  const int rb0 = lane & 15;
  const int ko = (lane >> 4) * 8;
  const int g = lane >> 4, c0 = lane & 15;

  f32x4 acc[12];
#pragma unroll
  for (int i = 0; i < 12; ++i) acc[i] = (f32x4){0.f, 0.f, 0.f, 0.f};

  for (int kc = 0; kc < HD; kc += 64) {
    if (kc) __syncthreads();
#pragma unroll
    for (int i = 0; i < 2; ++i) {             // A: W1 rows j0..j0+63
      const int c = i * 256 + tid;
      const int r = c >> 3, cb = c & 7;
      const u16x8 v = cvt8(Wf + (size_t)(j0 + r) * HD + kc + cb * 8);
      *reinterpret_cast<u16x8*>(&lds[r * 128 + ((cb * 16) ^ ((r & 7) << 4))]) = v;
    }
#pragma unroll
    for (int i = 0; i < 6; ++i) {             // B: [ec;es] rows 0..191
      const int c = i * 256 + tid;
      const int r = c >> 3, cb = c & 7;
      const float* src = (r < KCL) ? (ec + r * HD + kc + cb * 8)
                                   : (es + (r - KCL) * HD + kc + cb * 8);
      const u16x8 v = cvt8(src);
      *reinterpret_cast<u16x8*>(&lds[8192 + r * 128 + ((cb * 16) ^ ((r & 7) << 4))]) = v;
    }
    __syncthreads();
#pragma unroll
    for (int kk = 0; kk < 64; kk += 32) {
      const int kb = (kk + ko) * 2;
      const bh8 af = *reinterpret_cast<const bh8*>(&lds[ra * 128 + (kb ^ ((ra & 7) << 4))]);
#pragma unroll
      for (int nj = 0; nj < 12; ++nj) {
        const int rb = nj * 16 + rb0;
        const bh8 bf = *reinterpret_cast<const bh8*>(&lds[8192 + rb * 128 + (kb ^ ((rb & 7) << 4))]);
        acc[nj] = __builtin_amdgcn_mfma_f32_16x16x32_bf16(af, bf, acc[nj], 0, 0, 0);
      }
    }
  }

  // epilogue: P[r][j] = acc (+ b1[j] on ec rows r<128)
#pragma unroll
  for (int nj = 0; nj < 12; ++nj) {
    const int r = nj * 16 + c0;               // emb row 0..191
#pragma unroll
    for (int reg = 0; reg < 4; ++reg) {
      const int j = j0 + wid * 16 + g * 4 + reg;
      float v = acc[nj][reg];
      if (r < KCL) v += bias[j];
      P[(size_t)r * HD + j] = v;
    }
  }
}

// ---------------- mlp2_k: layer-2 GEMM, A = relu(P1+P2) in staging ----------------
// grid (4, 128, 3). LDS: A 8KB @0 | B 8KB @8192. 64x64 tile (R24 structure).

__global__ __launch_bounds__(256) void mlp2_k(
    const float* __restrict__ ec0, const float* __restrict__ es0,
    const float* __restrict__ ec1, const float* __restrict__ es1,
    const float* __restrict__ ec2, const float* __restrict__ es2,
    const float* __restrict__ Pb,
    const float* __restrict__ Wf0, const float* __restrict__ Wf1,
    const float* __restrict__ Wf2,
    const float* __restrict__ bb0, const float* __restrict__ bb1, const float* __restrict__ bb2,
    const float* __restrict__ sow, float* __restrict__ hlog,
    u16* __restrict__ Xbf, u16* __restrict__ PHb) {
  __shared__ char lds[16384];
  const int tid = threadIdx.x, lane = tid & 63, wid = tid >> 6;
  const int z = blockIdx.z;

  const float* ec = z == 0 ? ec0 : z == 1 ? ec1 : ec2;
  const float* es = z == 0 ? es0 : z == 1 ? es1 : es2;
  const float* Pz = Pb + (size_t)z * 192 * HD;
  const float* Wf = z == 0 ? Wf0 : z == 1 ? Wf1 : Wf2;
  const float* bias = z == 0 ? bb0 : z == 1 ? bb1 : bb2;

  const int rm = blockIdx.y * 64, cn = blockIdx.x * 64;
  const float* Bgf = Wf + (size_t)cn * HD;

  f32x4 acc[4];
#pragma unroll
  for (int i = 0; i < 4; ++i) acc[i] = (f32x4){0.f, 0.f, 0.f, 0.f};
  const int ra = wid * 16 + (lane & 15);
  const int rb0 = lane & 15;
  const int ko = (lane >> 4) * 8;

  for (int kc = 0; kc < HD; kc += 64) {
    if (kc) __syncthreads();
#pragma unroll
    for (int i = 0; i < 2; ++i) {
      const int c = i * 256 + tid;
      const int r = c >> 3, cb = c & 7;
      const int grow = rm + r;
      const int krow = grow >> 6, srow = grow & 63;
      const int h0 = kc + cb * 8;
      // A: H row = relu(P1[krow] + P2[srow]) (b1 already folded into P1)
      const u16x8 v = relu_add_cvt8(Pz + (size_t)krow * HD + h0,
                                    Pz + (size_t)(KCL + srow) * HD + h0);
      *reinterpret_cast<u16x8*>(&lds[r * 128 + ((cb * 16) ^ ((r & 7) << 4))]) = v;
      const u16x8 bv = cvt8(Bgf + (size_t)r * HD + kc + cb * 8);
      *reinterpret_cast<u16x8*>(&lds[8192 + r * 128 + ((cb * 16) ^ ((r & 7) << 4))]) = bv;
    }
    __syncthreads();
#pragma unroll
    for (int kk = 0; kk < 64; kk += 32) {
      const int kb = (kk + ko) * 2;
      const bh8 af = *reinterpret_cast<const bh8*>(&lds[ra * 128 + (kb ^ ((ra & 7) << 4))]);
#pragma unroll
      for (int nj = 0; nj < 4; ++nj) {
        const int rb = nj * 16 + rb0;
        const bh8 bf = *reinterpret_cast<const bh8*>(&lds[8192 + rb * 128 + (kb ^ ((rb & 7) << 4))]);
        acc[nj] = __builtin_amdgcn_mfma_f32_16x16x32_bf16(af, bf, acc[nj], 0, 0, 0);
      }
    }
  }

  const int g = lane >> 4, c0 = lane & 15;
  float pd[4] = {0.f, 0.f, 0.f, 0.f};
#pragma unroll
  for (int nj = 0; nj < 4; ++nj) {
    const int nidx = cn + nj * 16 + c0;
    const float bv = bias[nidx];
#pragma unroll
    for (int reg = 0; reg < 4; ++reg) {
      const int midx = rm + wid * 16 + g * 4 + reg;
      float v = acc[nj][reg] + bv
              + ec[(midx >> 6) * HD + nidx] + es[(midx & 63) * HD + nidx];
      v = fmaxf(v, 0.f);
      if (z == 0) pd[reg] += v * sow[nidx];
      else if (z == 1) Xbf[(size_t)midx * 256 + nidx] = f2bf(v);
      else PHb[(size_t)midx * 256 + nidx] = f2bf(v);
    }
  }
  if (blockIdx.z == 0) {
#pragma unroll
    for (int off = 1; off < 16; off <<= 1)
#pragma unroll
      for (int reg = 0; reg < 4; ++reg)
        pd[reg] += __shfl_xor(pd[reg], off, 64);
    if (c0 == 0) {
#pragma unroll
      for (int reg = 0; reg < 4; ++reg)
        atomicAdd(&hlog[rm + wid * 16 + g * 4 + reg], pd[reg]);
    }
  }
}

// ---------------- te_k: t12 GEMM + emission GEMM + hlse rider --------

__global__ __launch_bounds__(256) void te_k(
    const u16* __restrict__ Xbf, const float* __restrict__ nec,
    const float* __restrict__ nes,
    float* __restrict__ T12, float* __restrict__ rlse,
    const float* __restrict__ tpw, const u16* __restrict__ PHb,
    const float* __restrict__ bp,
    const int* __restrict__ offs, const int* __restrict__ wlist,
    const int* __restrict__ map,
    float* __restrict__ esum, float* __restrict__ logits_all,
    const float* __restrict__ hlog, float* __restrict__ hlseb) {
  __shared__ char lds[32768];
  const int tid = threadIdx.x, lane = tid & 63, wid = tid >> 6;
  const int rb0 = lane & 15;
  const int ko = (lane >> 4) * 8;
  const int g = lane >> 4, c0 = lane & 15;

  if (blockIdx.x == CS / 64 + MAXB) {
    // ---------- hlse rider: logsumexp over hlog[0..CS) ----------
    __shared__ float redm[4];
    float mm = -1e30f;
    for (int i = tid; i < CS; i += 256) mm = fmaxf(mm, hlog[i]);
    for (int off = 32; off; off >>= 1) mm = fmaxf(mm, __shfl_xor(mm, off, 64));
    if (lane == 0) redm[wid] = mm;
    __syncthreads();
    const float M = fmaxf(fmaxf(redm[0], redm[1]), fmaxf(redm[2], redm[3]));
    float sx = 0.f;
    for (int i = tid; i < CS; i += 256) sx += expf(hlog[i] - M);
    for (int off = 32; off; off >>= 1) sx += __shfl_xor(sx, off, 64);
    __syncthreads();
    if (lane == 0) redm[wid] = sx;
    __syncthreads();
    if (tid == 0) hlseb[0] = M + logf(redm[0] + redm[1] + redm[2] + redm[3]);
    return;
  }

  if (blockIdx.x < CS / 64) {
    // ---------- t12 part ----------
    const int rm = blockIdx.x * 64;
    const int ra = wid * 16 + (lane & 15);
    f32x4 acc[12];
#pragma unroll
    for (int i = 0; i < 12; ++i) acc[i] = (f32x4){0.f, 0.f, 0.f, 0.f};

    for (int kc = 0; kc < HD; kc += 64) {
      if (kc) __syncthreads();
#pragma unroll
      for (int i = 0; i < 2; ++i) {
        const int c = i * 256 + tid;
        const int r = c >> 3, cb = c & 7;
        const int gq = cb ^ (r & 7);
        gl2lds16(Xbf + (size_t)(rm + r) * HD + kc + gq * 8, (u16*)&lds[c * 16]);
      }
#pragma unroll
      for (int i = 0; i < 6; ++i) {
        const int c = i * 256 + tid;        // 0..1535 -> 192 rows x 8 chunks
        const int r = c >> 3, cb = c & 7;
        const float* src = (r < KCL) ? (nec + r * HD + kc + cb * 8)
                                     : (nes + (r - KCL) * HD + kc + cb * 8);
        const u16x8 v = cvt8(src);
        *reinterpret_cast<u16x8*>(&lds[8192 + r * 128 + ((cb * 16) ^ ((r & 7) << 4))]) = v;
      }
      __syncthreads();
#pragma unroll
      for (int kk = 0; kk < 64; kk += 32) {
        const int kb = (kk + ko) * 2;
        const bh8 af = *reinterpret_cast<const bh8*>(&lds[ra * 128 + (kb ^ ((ra & 7) << 4))]);
#pragma unroll
        for (int nj = 0; nj < 12; ++nj) {
          const int rb = nj * 16 + rb0;
          const bh8 bf = *reinterpret_cast<const bh8*>(&lds[8192 + rb * 128 + (kb ^ ((rb & 7) << 4))]);
          acc[nj] = __builtin_amdgcn_mfma_f32_16x16x32_bf16(af, bf, acc[nj], 0, 0, 0);
        }
      }
    }

    float rs1[4] = {0.f, 0.f, 0.f, 0.f};
    float rs2[4] = {0.f, 0.f, 0.f, 0.f};
#pragma unroll
    for (int nj = 0; nj < 12; ++nj) {
      const int col = nj * 16 + c0;
#pragma unroll
      for (int reg = 0; reg < 4; ++reg) {
        const int row = rm + wid * 16 + g * 4 + reg;
        const float v = acc[nj][reg];
        T12[(size_t)row * 192 + col] = v;
        const float e = exp2f(v * LOG2E);
        if (nj < 8) rs1[reg] += e; else rs2[reg] += e;
      }
    }
#pragma unroll
    for (int off = 1; off < 16; off <<= 1)
#pragma unroll
      for (int reg = 0; reg < 4; ++reg) {
        rs1[reg] += __shfl_xor(rs1[reg], off, 64);
        rs2[reg] += __shfl_xor(rs2[reg], off, 64);
      }
    if (c0 == 0) {
#pragma unroll
      for (int reg = 0; reg < 4; ++reg)
        rlse[rm + wid * 16 + g * 4 + reg] = logf(rs1[reg]) + logf(rs2[reg]);
    }
    return;
  }

  // ---------- emission part ----------
  const int ent = map[blockIdx.x - CS / 64];
  if (ent < 0) return;
  const int c = ent >> 8, blk = ent & 255;
  __shared__ int wid_s[64];
  const int st = offs[c], cnt = offs[c + 1] - st;
  if (tid < 64) {
    const int idx = blk * 64 + tid;
    wid_s[tid] = (idx < cnt) ? wlist[st + idx] : -1;
  }
  __syncthreads();

  f32x4 acc[4];
#pragma unroll
  for (int i = 0; i < 4; ++i) acc[i] = (f32x4){0.f, 0.f, 0.f, 0.f};
  const int ra = wid * 16 + (lane & 15);
  const u16* Bg = PHb + (size_t)(c * 64) * HD;

  for (int kc = 0; kc < HD; kc += 64) {
    if (kc) __syncthreads();
#pragma unroll
    for (int i = 0; i < 2; ++i) {
      const int cc = i * 256 + tid;
      const int r = cc >> 3, cb = cc & 7;
      const int gq = cb ^ (r & 7);
      const int wv = max(wid_s[r], 0);
      const u16x8 av = cvt8(tpw + (size_t)wv * HD + kc + cb * 8);
      *reinterpret_cast<u16x8*>(&lds[r * 128 + ((cb * 16) ^ ((r & 7) << 4))]) = av;
      gl2lds16(Bg + (size_t)r * HD + kc + gq * 8, (u16*)&lds[8192 + cc * 16]);
    }
    __syncthreads();
#pragma unroll
    for (int kk = 0; kk < 64; kk += 32) {
      const int kb = (kk + ko) * 2;
      const bh8 af = *reinterpret_cast<const bh8*>(&lds[ra * 128 + (kb ^ ((ra & 7) << 4))]);
#pragma unroll
      for (int nj = 0; nj < 4; ++nj) {
        const int rb = nj * 16 + rb0;
        const bh8 bf = *reinterpret_cast<const bh8*>(&lds[8192 + rb * 128 + (kb ^ ((rb & 7) << 4))]);
        acc[nj] = __builtin_amdgcn_mfma_f32_16x16x32_bf16(af, bf, acc[nj], 0, 0, 0);
      }
    }
  }

#pragma unroll
  for (int nj = 0; nj < 4; ++nj) {
    float se = 0.f;
#pragma unroll
    for (int reg = 0; reg < 4; ++reg) {
      const int row = wid * 16 + g * 4 + reg;
      const int w = wid_s[row];
      if (w >= 0) {
        const float lg = acc[nj][reg] + bp[w];
        logits_all[(size_t)w * 64 + nj * 16 + c0] = lg;
        se += expf(lg);
      }
    }
    se += __shfl_xor(se, 16, 64);
    se += __shfl_xor(se, 32, 64);
    if (g == 0) atomicAdd(&esum[c * 64 + nj * 16 + c0], se);
  }
}

// ---------------- quad combine core (32KB LDS: P/ftile reuse dead slots) --------

__device__ __forceinline__ void comb4_core(
    char* lds, float* wpm,
    float sc0, float sc1, float sc2, float sc3,
    u16* node, float* dsc, int parity, int tid) {
  const int lane = tid & 63, w = tid >> 6;
  const int p = w >> 1, h = w & 1;
  const int abase = p * 16384, bbase = abase + 8192;
  const int c0 = lane & 15, g = lane >> 4;
  f32x4 a2[2][4];
#pragma unroll
  for (int mi = 0; mi < 2; ++mi)
#pragma unroll
    for (int nj = 0; nj < 4; ++nj) a2[mi][nj] = (f32x4){0.f, 0.f, 0.f, 0.f};
#pragma unroll
  for (int kk = 0; kk < 64; kk += 32) {
    const int kb = (kk + g * 8) * 2;
    bh8 af[2], bf[4];
#pragma unroll
    for (int mi = 0; mi < 2; ++mi) {
      const int ar = h * 32 + mi * 16 + c0;
      af[mi] = *reinterpret_cast<const bh8*>(&lds[abase + ar * 128 + (kb ^ ((ar & 7) << 4))]);
    }
#pragma unroll
    for (int nj = 0; nj < 4; ++nj) {
      const int br = nj * 16 + c0;
      bf[nj] = *reinterpret_cast<const bh8*>(&lds[bbase + br * 128 + (kb ^ ((br & 7) << 4))]);
    }
#pragma unroll
    for (int mi = 0; mi < 2; ++mi)
#pragma unroll
      for (int nj = 0; nj < 4; ++nj)
        a2[mi][nj] = __builtin_amdgcn_mfma_f32_16x16x32_bf16(af[mi], bf[nj], a2[mi][nj], 0, 0, 0);
  }
  float mx = 0.f;
#pragma unroll
  for (int mi = 0; mi < 2; ++mi)
#pragma unroll
    for (int nj = 0; nj < 4; ++nj)
#pragma unroll
      for (int reg = 0; reg < 4; ++reg) mx = fmaxf(mx, a2[mi][nj][reg]);
#pragma unroll
  for (int off = 1; off < 64; off <<= 1) mx = fmaxf(mx, __shfl_xor(mx, off, 64));
  if (lane == 0) wpm[w] = mx;
  __syncthreads();                 // all stage-1 MFMAs done -> slots 0..3 dead
  const float mp = fmaxf(wpm[p * 2], wpm[p * 2 + 1]);
  const float invp = 1.0f / mp;
#pragma unroll
  for (int mi = 0; mi < 2; ++mi)
#pragma unroll
    for (int nj = 0; nj < 4; ++nj)
#pragma unroll
      for (int reg = 0; reg < 4; ++reg) {
        const int row = h * 32 + mi * 16 + g * 4 + reg;
        const int col = nj * 16 + c0;
        const u16 val = f2bf(a2[mi][nj][reg] * invp);
        if (p == 0)                // P1 -> slot0 region (@0)
          *reinterpret_cast<u16*>(&lds[row * 128 + ((col * 2) ^ ((row & 7) << 4))]) = val;
        else                       // P2 -> slot1 region (@8192), transposed
          *reinterpret_cast<u16*>(&lds[8192 + col * 128 + ((row * 2) ^ ((col & 7) << 4))]) = val;
      }
  __syncthreads();

  f32x4 acc[4];
#pragma unroll
  for (int i = 0; i < 4; ++i) acc[i] = (f32x4){0.f, 0.f, 0.f, 0.f};
  const int ra = w * 16 + c0;
#pragma unroll
  for (int kk = 0; kk < 64; kk += 32) {
    const int kb = (kk + g * 8) * 2;
    const bh8 af = *reinterpret_cast<const bh8*>(&lds[ra * 128 + (kb ^ ((ra & 7) << 4))]);
#pragma unroll
    for (int nj = 0; nj < 4; ++nj) {
      const int rb = nj * 16 + c0;
      const bh8 bf = *reinterpret_cast<const bh8*>(&lds[8192 + rb * 128 + (kb ^ ((rb & 7) << 4))]);
      acc[nj] = __builtin_amdgcn_mfma_f32_16x16x32_bf16(af, bf, acc[nj], 0, 0, 0);
    }
  }
  float mx2 = 0.f;
#pragma unroll
  for (int nj = 0; nj < 4; ++nj)
#pragma unroll
    for (int reg = 0; reg < 4; ++reg) mx2 = fmaxf(mx2, acc[nj][reg]);
#pragma unroll
  for (int off = 1; off < 64; off <<= 1) mx2 = fmaxf(mx2, __shfl_xor(mx2, off, 64));
  if (lane == 0) wpm[4 + w] = mx2;
  __syncthreads();                 // all stage-2 MFMAs done -> P1/P2 dead
  const float m = fmaxf(fmaxf(wpm[4], wpm[5]), fmaxf(wpm[6], wpm[7]));
  const float inv = 1.0f / m;
  float* ftile = reinterpret_cast<float*>(lds + 16384);   // reuses slots 2-3
#pragma unroll
  for (int nj = 0; nj < 4; ++nj)
#pragma unroll
    for (int reg = 0; reg < 4; ++reg)
      ftile[(w * 16 + g * 4 + reg) * 64 + nj * 16 + c0] = acc[nj][reg] * inv;
  __syncthreads();
  const int rr = tid >> 2, cb = (tid & 3) * 16;
  u16x8 o0, o1;
  if (parity == 0) {
#pragma unroll
    for (int e = 0; e < 8; ++e) o0[e] = f2bf(ftile[rr * 64 + cb + e]);
#pragma unroll
    for (int e = 0; e < 8; ++e) o1[e] = f2bf(ftile[rr * 64 + cb + 8 + e]);
  } else {
#pragma unroll
    for (int e = 0; e < 8; ++e) o0[e] = f2bf(ftile[(cb + e) * 64 + rr]);
#pragma unroll
    for (int e = 0; e < 8; ++e) o1[e] = f2bf(ftile[(cb + 8 + e) * 64 + rr]);
  }
  *reinterpret_cast<u16x8*>(node + rr * 64 + cb) = o0;
  *reinterpret_cast<u16x8*>(node + rr * 64 + cb + 8) = o1;
  if (tid == 0)
    *dsc = sc0 + sc1 + sc2 + sc3
         + logf(fmaxf(wpm[0], wpm[1])) + logf(fmaxf(wpm[2], wpm[3])) + logf(m);
}

__device__ __forceinline__ void comb4_stage(
    char* lds, const u16* s0, const u16* s1, const u16* s2, const u16* s3, int tid) {
  const u16* srcs[4] = {s0, s1, s2, s3};
  const int sr = tid >> 3, scb = (tid & 7) * 16;
#pragma unroll
  for (int nd = 0; nd < 4; ++nd)
#pragma unroll
    for (int rep = 0; rep < 2; ++rep) {
      const int r = rep * 32 + sr;
      const bh8 v = *reinterpret_cast<const bh8*>(srcs[nd] + r * 64 + (scb >> 1));
      *reinterpret_cast<bh8*>(&lds[nd * 8192 + r * 128 + (scb ^ ((r & 7) << 4))]) = v;
    }
  __syncthreads();
}

// ---------------- leafc2_k: 4 elementwise leaves in LDS + combine ----------------

__global__ __launch_bounds__(256) void leafc2_k(
    const float* __restrict__ T12, const float* __restrict__ rlse,
    const float* __restrict__ lall, const float* __restrict__ esum,
    const int* __restrict__ text, const int* __restrict__ w2c,
    u16* __restrict__ dst, float* __restrict__ scd) {
  __shared__ char lds[32768];
  __shared__ float wpm[8];
  __shared__ float scl[4];
  __shared__ float ev_s[64];
  const int tid = threadIdx.x, lane = tid & 63, w = tid >> 6;
  const int n = blockIdx.x >> 6, u = blockIdx.x & 63;
  const int r = tid >> 2, cb = (tid & 3) * 16;

  for (int j = 0; j < 4; ++j) {
    const int l = 4 * u + j;
    char* slot = &lds[j * 8192];
    __syncthreads();
    if (l == 255) {
      for (int idx = tid; idx < 4096; idx += 256) {
        const int rr = idx >> 6, cc = idx & 63;
        const u16 val = (rr == cc) ? (u16)0x3F80 : (u16)0;
        *reinterpret_cast<u16*>(&slot[cc * 128 + ((rr * 2) ^ ((cc & 7) << 4))]) = val;
      }
      if (tid == 0) scl[j] = 0.f;
      continue;
    }
    const int ttv = l + 1;
    const int wcur = text[n * TT + ttv];
    const int cp = w2c[text[n * TT + ttv - 1]];
    const int cc = w2c[wcur];
    if (tid < 64)
      ev_s[tid] = lall[(size_t)wcur * 64 + tid] - logf(esum[cc * 64 + tid]);
    __syncthreads();
    const int grow = cp * 64 + r;
    const float base = T12[(size_t)grow * 192 + cc] - rlse[grow];
    const float* t2row = T12 + (size_t)grow * 192 + 128 + cb;
    float L[16];
    float mx = -1e30f;
#pragma unroll
    for (int e = 0; e < 16; ++e) {
      L[e] = base + t2row[e] + ev_s[cb + e];
      mx = fmaxf(mx, L[e]);
    }
#pragma unroll
    for (int off = 1; off < 64; off <<= 1) mx = fmaxf(mx, __shfl_xor(mx, off, 64));
    if (lane == 0) wpm[w] = mx;
    __syncthreads();
    const float m = fmaxf(fmaxf(wpm[0], wpm[1]), fmaxf(wpm[2], wpm[3]));
    if ((j & 1) == 0) {
      u16x8 o0, o1;
#pragma unroll
      for (int e = 0; e < 8; ++e) o0[e] = f2bf(exp2f((L[e] - m) * LOG2E));
#pragma unroll
      for (int e = 0; e < 8; ++e) o1[e] = f2bf(exp2f((L[8 + e] - m) * LOG2E));
      const int sw = (r & 7) << 4;
      *reinterpret_cast<u16x8*>(&slot[r * 128 + ((cb * 2) ^ sw)]) = o0;
      *reinterpret_cast<u16x8*>(&slot[r * 128 + ((cb * 2 + 16) ^ sw)]) = o1;
    } else {
#pragma unroll
      for (int e = 0; e < 16; ++e) {
        const int col = cb + e;
        const u16 val = f2bf(exp2f((L[e] - m) * LOG2E));
        *reinterpret_cast<u16*>(&slot[col * 128 + ((r * 2) ^ ((col & 7) << 4))]) = val;
      }
    }
    if (tid == 0) scl[j] = m;
  }
  __syncthreads();
  comb4_core(lds, wpm, scl[0], scl[1], scl[2], scl[3],
             dst + ((size_t)(n * 64 + u)) * 4096, &scd[n * 64 + u], u & 1, tid);
}

__global__ __launch_bounds__(256) void comb4_k(const u16* __restrict__ src,
                                               const float* __restrict__ scs,
                                               u16* __restrict__ dst,
                                               float* __restrict__ scd, int U) {
  const int n = blockIdx.x / U, u = blockIdx.x % U;
  __shared__ char lds[32768];
  __shared__ float wpm[8];
  const u16* base = src + ((size_t)(n * 4 * U + 4 * u)) * 4096;
  const float* sb = scs + n * 4 * U + 4 * u;
  comb4_stage(lds, base, base + 4096, base + 2 * 4096, base + 3 * 4096, threadIdx.x);
  comb4_core(lds, wpm, sb[0], sb[1], sb[2], sb[3],
             dst + ((size_t)(n * U + u)) * 4096, &scd[n * U + u], u & 1, threadIdx.x);
}

// ---------------- tail2: 4 -> 1 + final (hlse precomputed by te_k rider) --------

__global__ __launch_bounds__(256) void tail2_k(
    const u16* __restrict__ nodes, const float* __restrict__ nsc,
    u16* __restrict__ rootb,
    const float* __restrict__ hlog, const float* __restrict__ hlseb,
    const float* __restrict__ lall,
    const float* __restrict__ esum, const int* __restrict__ text,
    const int* __restrict__ w2c, float* __restrict__ out) {
  __shared__ char lds[32768];
  __shared__ float wpm[8];
  __shared__ float rsc_s;
  const int n = blockIdx.x, tid = threadIdx.x;

  const u16* src = nodes + (size_t)n * 4 * 4096;
  const float* sc = nsc + n * 4;
  u16* root = rootb + (size_t)n * 4096;
  comb4_stage(lds, src, src + 4096, src + 2 * 4096, src + 3 * 4096, tid);
  comb4_core(lds, wpm, sc[0], sc[1], sc[2], sc[3], root, &rsc_s, 0, tid);
  __syncthreads();

  if (tid < 64) {
    const int i = tid;
    const float hlse = hlseb[0];
    const int w0 = text[n * TT];
    const int cc = w2c[w0];
    const float ev = lall[(size_t)w0 * 64 + i] - logf(esum[cc * 64 + i]);
    float a0 = hlog[cc * 64 + i] - hlse + ev;
    float m0 = a0;
    for (int off = 32; off; off >>= 1) m0 = fmaxf(m0, __shfl_xor(m0, off, 64));
    const float lin = expf(a0 - m0);
    const u16* row = root + i * 64;
    float rs = 0.f;
#pragma unroll
    for (int e8 = 0; e8 < 8; ++e8) {
      const u16x8 v = *reinterpret_cast<const u16x8*>(row + e8 * 8);
#pragma unroll
      for (int e = 0; e < 8; ++e) rs += bf2f(v[e]);
    }
    float v = lin * rs;
    for (int off = 32; off; off >>= 1) v += __shfl_xor(v, off, 64);
    if (i == 0) out[n] = m0 + rsc_s + logf(v);
  }
}

// ---------------- host orchestration ----------------

extern "C" void kernel_launch(void* const* d_in, const int* in_sizes, int n_in,
                              void* d_out, int out_size, void* d_ws, size_t ws_size,
                              hipStream_t stream) {
  (void)in_sizes; (void)n_in; (void)out_size; (void)ws_size;
  const int* text = (const int*)d_in[0];
  const int* w2c  = (const int*)d_in[1];
  const float* sec = (const float*)d_in[2];
  const float* ses = (const float*)d_in[3];
  const float* stc = (const float*)d_in[4];
  const float* sts = (const float*)d_in[5];
  const float* nec = (const float*)d_in[6];
  const float* nes = (const float*)d_in[7];
  const float* pec = (const float*)d_in[8];
  const float* pes = (const float*)d_in[9];
  const float* srw1 = (const float*)d_in[10];
  const float* srb1 = (const float*)d_in[11];
  const float* srw2 = (const float*)d_in[12];
  const float* srb2 = (const float*)d_in[13];
  const float* trw1 = (const float*)d_in[14];
  const float* trb1 = (const float*)d_in[15];
  const float* trw2 = (const float*)d_in[16];
  const float* trb2 = (const float*)d_in[17];
  const float* tew1 = (const float*)d_in[18];
  const float* teb1 = (const float*)d_in[19];
  const float* tew2 = (const float*)d_in[20];
  const float* teb2 = (const float*)d_in[21];
  const float* sow = (const float*)d_in[22];
  const float* sob = (const float*)d_in[23];
  const float* tpw = (const float*)d_in[24];
  const float* tpb = (const float*)d_in[25];
  float* out = (float*)d_out;

  char* p = (char*)d_ws;
  auto carve = [&](size_t bytes) -> char* {
    char* r = p; p += (bytes + 255) & ~(size_t)255; return r;
  };
  float* Pb  = (float*)carve((size_t)3 * 192 * HD * 4);
  u16* Xbf  = (u16*)carve((size_t)CS * HD * 2);
  u16* PHb  = (u16*)carve((size_t)CS * HD * 2);
  float* T12  = (float*)carve((size_t)CS * 192 * 4);
  float* hlog  = (float*)carve(CS * 4);
  float* rlse  = (float*)carve(CS * 4);
  float* hlseb = (float*)carve(256);
  int* offs    = (int*)carve((KCL + 1) * 4);
  int* wlist   = (int*)carve(VV * 4);
  int* bmap    = (int*)carve(MAXB * 4);
  float* esum  = (float*)carve(CS * 4);
  float* lall  = (float*)carve((size_t)VV * 64 * 4);
  u16*   bufA  = (u16*)carve((size_t)NB * 64 * 4096 * 2);   // L1 out
  u16*   bufB  = (u16*)carve((size_t)NB * 16 * 4096 * 2);   // L2 out
  u16*   bufC  = (u16*)carve((size_t)NB * 4 * 4096 * 2);    // L3 out
  u16*   rootb = (u16*)carve((size_t)NB * 4096 * 2);
  float* scA   = (float*)carve((size_t)NB * 64 * 4);
  float* scB   = (float*)carve((size_t)NB * 16 * 4);
  float* scC   = (float*)carve((size_t)NB * 4 * 4);

  // P = [ec;es] @ W1^T (b1 folded) + CSR/init rider (y==3)
  p12_k<<<dim3(4, 4), 256, 0, stream>>>(
      sec, ses, stc, sts, pec, pes,
      srw1, trw1, tew1, srb1, trb1, teb1,
      Pb, w2c, offs, wlist, bmap, esum, hlog, sob);

  // layer-2 GEMM; A = relu(P1+P2) built in staging (head dot fused at z==0)
  mlp2_k<<<dim3(4, 128, 3), 256, 0, stream>>>(
      sec, ses, stc, sts, pec, pes, Pb,
      srw2, trw2, tew2, srb2, trb2, teb2,
      sow, hlog, Xbf, PHb);

  // t12 GEMM + emission + hlse rider in one launch
  te_k<<<CS / 64 + MAXB + 1, 256, 0, stream>>>(
      Xbf, nec, nes, T12, rlse, tpw, PHb, tpb, offs, wlist, bmap, esum, lall,
      hlog, hlseb);

  // fused elementwise-leaf + level-1 combine: 256 leaves -> 64 nodes per seq
  leafc2_k<<<NB * 64, 256, 0, stream>>>(
      T12, rlse, lall, esum, text, w2c, bufA, scA);

  comb4_k<<<NB * 16, 256, 0, stream>>>(bufA, scA, bufB, scB, 16);
  comb4_k<<<NB * 4, 256, 0, stream>>>(bufB, scB, bufC, scC, 4);
  tail2_k<<<NB, 256, 0, stream>>>(bufC, scC, rootb, hlog, hlseb, lall, esum,
                                  text, w2c, out);
}